// Round 11
// baseline (524.184 us; speedup 1.0000x reference)
//
#include <hip/hip_runtime.h>
#include <math.h>

// 2-layer ReLU RNN, B=256, T=1000 (input 800 + zero pad), H=128, F=5.
// R11 = R10 (best: 508us) with g0+g1 merged into one gAB role:
//   gAB (4 wv): h0[s] = relu(Whh0.h0[s-1] + Wih0.x[s] + b0)  then
//               A[s-1] = Wih1.h0[s-1] + b1    -- ONE shared h0 b128 read
//   gC  (4 wv): h1[s-2] = relu(A[s-2] + Whh1.h1[s-3] + b1(in A_f))
//               + DPP-only y-dots every 16 steps (R10 scheme)
// Why: R10 step = 1120 cyc with only ~330 cyc/SIMD of real issue; the rest
// is a 12-wave barrier convoy + DS latency. 512 thr = 8 waves halves convoy
// membership, removes 4 duplicate h0 reads/step, and pairs exactly
// 1 gAB + 1 gC per SIMD: role=(wv^(wv>>2))&1, sub=wv>>1 are robust under
// both wv%4 and wv/2 wave->SIMD mappings (R8's mistake was 128 blocks +
// 4 waves/SIMD, not the merge). gAB: recurrence-critical h0 chain ordered
// first (dots->reduce->relu->ds_write), then A dots; s_setprio(1) on gAB.
// 8x8 tiles, XOR-linear row map, all-DPP 16-lane reduce (R2/R7-verified).
// No global ops in the step loop.

#define TT    1000
#define TIN   800
#define HD    128
#define NF    5
#define BATCH 256

typedef _Float16 h16x2 __attribute__((ext_vector_type(2)));
typedef _Float16 h16x8 __attribute__((ext_vector_type(8)));

template<int CTRL>
__device__ __forceinline__ float dpp_mov(float v) {
    union { float f; int i; } u, r;
    u.f = v;
    r.i = __builtin_amdgcn_update_dpp(0, u.i, CTRL, 0xF, 0xF, true);
    return r.f;
}

__global__ __launch_bounds__(512, 2) void rnn_fused(
    const float* __restrict__ x,        // [256,800,5]
    const float* __restrict__ h_state,  // [2,256,128]
    const float* __restrict__ w_ih0,    // [128,5]
    const float* __restrict__ w_hh0,    // [128,128]
    const float* __restrict__ b_ih0,    // [128]
    const float* __restrict__ b_hh0,    // [128]
    const float* __restrict__ w_ih1,    // [128,128]
    const float* __restrict__ w_hh1,    // [128,128]
    const float* __restrict__ b_ih1,    // [128]
    const float* __restrict__ b_hh1,    // [128]
    const float* __restrict__ w_out,    // [1,128]
    const float* __restrict__ b_out,    // [1]
    float* __restrict__ out)            // [204800 y] ++ [65536 final states]
{
    __shared__ __align__(16) _Float16 x_h[TIN * 8];      // fp16, 12.8 KB
    __shared__ __align__(16) _Float16 h0h[2][HD];
    __shared__ __align__(16) _Float16 h1h[2][HD];
    __shared__ float A_f[2][HD];                         // pre-act incl. b1
    __shared__ __align__(16) _Float16 ring[32][HD];      // h1 history, 8 KB
    __shared__ float y_lds[TIN];                         // 3.2 KB

    const int tid  = threadIdx.x;
    const int bb   = blockIdx.x;
    const int wv   = tid >> 6;                 // 0..7
    const int lane = tid & 63;
    const int role = (wv ^ (wv >> 2)) & 1;     // 0 = gAB, 1 = gC
    const int sub  = wv >> 1;                  // 0..3 within role (see map)
    const int it   = (sub << 6) | lane;        // 0..255 within role
    const int c    = it & 15;                  // col chunk / reduction lane
    const int rg   = it >> 4;                  // row group (8 rows)
    const int g    = (4 * (c & 1)) ^ (2 * ((c >> 1) & 1)) ^ (7 * ((c >> 2) & 1));
    const int row  = rg * 8 + g;               // row this thread finalizes
    const bool writer = (c & 8) == 0;

    // ---- stage x (fp16, stride 8, pads zero) + h-state ----
    for (int i = tid; i < TIN * 8; i += 512) x_h[i] = (_Float16)0.f;
    __syncthreads();
    for (int i = tid; i < TIN * NF; i += 512) {
        int t = i / 5, f = i - 5 * t;
        x_h[t * 8 + f] = (_Float16)x[bb * (TIN * NF) + i];
    }
    if (tid < HD) {
        h0h[0][tid] = (_Float16)h_state[bb * HD + tid];
        h1h[0][tid] = (_Float16)h_state[BATCH * HD + bb * HD + tid];
    }

    // ---- resident weights: 8x8 tiles, rows rg*8+(j^g), cols c*8..+7 ----
    h16x2 wA[8][4], wB[8][4];
    {
        const float* Wa = (role == 0) ? w_hh0 : w_hh1;
        #pragma unroll
        for (int j = 0; j < 8; ++j) {
            const float* rp = Wa + (rg * 8 + (j ^ g)) * HD + c * 8;
            #pragma unroll
            for (int t = 0; t < 4; ++t) {
                h16x2 w2 = { (_Float16)rp[2 * t], (_Float16)rp[2 * t + 1] };
                wA[j][t] = w2;
            }
        }
    }
    if (role == 0) {
        #pragma unroll
        for (int j = 0; j < 8; ++j) {
            const float* rp = w_ih1 + (rg * 8 + (j ^ g)) * HD + c * 8;
            #pragma unroll
            for (int t = 0; t < 4; ++t) {
                h16x2 w2 = { (_Float16)rp[2 * t], (_Float16)rp[2 * t + 1] };
                wB[j][t] = w2;
            }
        }
    }
    h16x2 wx0 = {0,0}, wx1 = {0,0}, wx2 = {0,0};   // gAB: Wih0 row
    h16x2 wo[4];                                    // gC: wout chunk
    float bias0 = 0.f, bias1 = 0.f;
    if (role == 0) {
        wx0[0] = (_Float16)w_ih0[row * NF + 0];
        wx0[1] = (_Float16)w_ih0[row * NF + 1];
        wx1[0] = (_Float16)w_ih0[row * NF + 2];
        wx1[1] = (_Float16)w_ih0[row * NF + 3];
        wx2[0] = (_Float16)w_ih0[row * NF + 4];
        bias0 = b_ih0[row] + b_hh0[row];
        bias1 = b_ih1[row] + b_hh1[row];
    } else {
        const int l4 = it & 15;
        #pragma unroll
        for (int t = 0; t < 4; ++t) {
            wo[t][0] = (_Float16)w_out[l4 * 8 + 2 * t];
            wo[t][1] = (_Float16)w_out[l4 * 8 + 2 * t + 1];
        }
    }
    const float bout = b_out[0];

    float hfin = 0.f;   // gAB writer: h0[999]; gC writer: h1[999]

    // 8x8 tile dots + all-DPP 16-lane reduction.
    auto tile_dot = [&](const h16x2 (&W)[8][4], h16x8 hv) -> float {
        h16x2 hp0 = { hv[0], hv[1] }, hp1 = { hv[2], hv[3] };
        h16x2 hp2 = { hv[4], hv[5] }, hp3 = { hv[6], hv[7] };
        float a[8];
        #pragma unroll
        for (int j = 0; j < 8; ++j) {
            float aj;
            aj = __builtin_amdgcn_fdot2(W[j][0], hp0, 0.f, false);
            aj = __builtin_amdgcn_fdot2(W[j][1], hp1, aj,  false);
            aj = __builtin_amdgcn_fdot2(W[j][2], hp2, aj,  false);
            aj = __builtin_amdgcn_fdot2(W[j][3], hp3, aj,  false);
            a[j] = aj;
        }
        a[0] += dpp_mov<0xB1>(a[4]);   // xor1
        a[1] += dpp_mov<0xB1>(a[5]);
        a[2] += dpp_mov<0xB1>(a[6]);
        a[3] += dpp_mov<0xB1>(a[7]);
        a[0] += dpp_mov<0x4E>(a[2]);   // xor2
        a[1] += dpp_mov<0x4E>(a[3]);
        a[0] += dpp_mov<0x140>(a[1]);  // xor15 (row_mirror)
        a[0] += dpp_mov<0x128>(a[0]);  // xor8  (row_ror:8)
        return a[0];
    };

    if (role == 0) __builtin_amdgcn_s_setprio(1);   // gAB is the long pole

    __syncthreads();

    #pragma unroll 2
    for (int s = 0; s < TT + 2; ++s) {
        const int p = s & 1;
        const int q = p ^ 1;

        if (role == 0) {
            if (s <= TT) {
                // shared h0[s-1] read serves both tiles
                h16x8 hv = *(const h16x8*)(&h0h[p][c * 8]);
                // --- critical: h0[s] first ---
                if (s < TT) {
                    float ra = tile_dot(wA, hv);
                    float v = ra + bias0;
                    if (s < TIN) {
                        h16x8 xv = *(const h16x8*)(&x_h[s * 8]);
                        h16x2 xp0 = { xv[0], xv[1] }, xp1 = { xv[2], xv[3] };
                        h16x2 xp2 = { xv[4], xv[5] };
                        float xc = __builtin_amdgcn_fdot2(wx2, xp2, 0.f, false);
                        xc = __builtin_amdgcn_fdot2(wx1, xp1, xc, false);
                        xc = __builtin_amdgcn_fdot2(wx0, xp0, xc, false);
                        v += xc;
                    }
                    v = fmaxf(v, 0.f);
                    if (writer) {
                        h0h[q][row] = (_Float16)v;
                        if (s == TT - 1) hfin = v;
                    }
                }
                // --- then A[s-1] = Wih1.h0[s-1] + b1 ---
                float rb = tile_dot(wB, hv);
                if (writer) A_f[q][row] = rb + bias1;
            }
        } else {
            // gC: h1[s-2] = relu(A[s-2] + Whh1.h1[s-3])
            if (s >= 2) {
                const int u = s - 2;
                h16x8 hv = *(const h16x8*)(&h1h[p][c * 8]);
                float pre = A_f[p][row];
                float ra = tile_dot(wA, hv);
                float v = fmaxf(ra + pre, 0.f);
                if (writer) {
                    _Float16 vh = (_Float16)v;
                    h1h[q][row] = vh;
                    if (u < TIN) ring[u & 31][row] = vh;
                    if (u == TT - 1) hfin = v;
                }
            }
            // y-dots every 16 steps: 16 slots x 16 lanes, DPP-only reduce
            if (s >= 18 && s <= 818 && ((s - 2) & 15) == 0) {
                const int u  = (s - 33) + (it >> 4);
                const int l4 = it & 15;
                if (u >= 0 && u < TIN) {
                    h16x8 hv = *(const h16x8*)(&ring[u & 31][l4 * 8]);
                    h16x2 hp0 = { hv[0], hv[1] }, hp1 = { hv[2], hv[3] };
                    h16x2 hp2 = { hv[4], hv[5] }, hp3 = { hv[6], hv[7] };
                    float z;
                    z = __builtin_amdgcn_fdot2(wo[0], hp0, 0.f, false);
                    z = __builtin_amdgcn_fdot2(wo[1], hp1, z,  false);
                    z = __builtin_amdgcn_fdot2(wo[2], hp2, z,  false);
                    z = __builtin_amdgcn_fdot2(wo[3], hp3, z,  false);
                    z += dpp_mov<0xB1>(z);    // xor1
                    z += dpp_mov<0x4E>(z);    // xor2
                    z += dpp_mov<0x140>(z);   // xor15
                    z += dpp_mov<0x128>(z);   // xor8
                    if (l4 == 0) y_lds[u] = 1.f / (1.f + expf(-(z + bout)));
                }
            }
        }
        __syncthreads();
    }

    // ---- epilogue: single global dump ----
    for (int i = tid; i < TIN; i += 512)
        out[bb * TIN + i] = y_lds[i];
    if (role == 0 && writer)
        out[TIN * BATCH + bb * HD + row] = hfin;
    if (role == 1 && writer)
        out[TIN * BATCH + BATCH * HD + bb * HD + row] = hfin;
}

extern "C" void kernel_launch(void* const* d_in, const int* in_sizes, int n_in,
                              void* d_out, int out_size, void* d_ws, size_t ws_size,
                              hipStream_t stream) {
    (void)in_sizes; (void)n_in; (void)d_ws; (void)ws_size; (void)out_size;
    rnn_fused<<<dim3(BATCH), dim3(512), 0, stream>>>(
        (const float*)d_in[0],  (const float*)d_in[1],
        (const float*)d_in[2],  (const float*)d_in[3],
        (const float*)d_in[4],  (const float*)d_in[5],
        (const float*)d_in[6],  (const float*)d_in[7],
        (const float*)d_in[8],  (const float*)d_in[9],
        (const float*)d_in[10], (const float*)d_in[11],
        (float*)d_out);
}